// Round 1
// baseline (276.144 us; speedup 1.0000x reference)
//
#include <hip/hip_runtime.h>
#include <math.h>

// Problem constants (ImprovedSpeMamba)
#define NROWS 32768      // b*c*h ; each row = W=128 floats = 4 tokens x 32 group
#define WPB 4            // waves per block
#define THREADS 256

__device__ __forceinline__ float dot4(float4 a, float4 b) {
    return a.x*b.x + a.y*b.y + a.z*b.z + a.w*b.w;
}
__device__ __forceinline__ float silu_f(float v) { return v / (1.f + __expf(-v)); }

// ---------------------------------------------------------------------------
// K1: fused mamba per row (wave per row). Writes xr into d_out, accumulates
// per-(b,c) sum / sumsq into S1/S2 (256 floats each) for SE + GroupNorm.
// ---------------------------------------------------------------------------
__global__ __launch_bounds__(256) void k_mamba(
    const float* __restrict__ x,
    const float* __restrict__ in_proj_w,   // (128,32)
    const float* __restrict__ conv_w,      // (64,4)
    const float* __restrict__ conv_b,      // (64)
    const float* __restrict__ x_proj_w,    // (34,64)
    const float* __restrict__ dt_proj_w,   // (64,2)
    const float* __restrict__ dt_proj_b,   // (64)
    const float* __restrict__ A_log,       // (64,16)
    const float* __restrict__ Dvec,        // (64)
    const float* __restrict__ out_proj_w,  // (32,64)
    float* __restrict__ xr,                // d_out reused as scratch (4M floats)
    float* __restrict__ S1,
    float* __restrict__ S2)
{
    // LDS: padded strides chosen for <=2-way bank aliasing (free) on reads.
    __shared__ __align__(16) float ipw[128*34];   // in_proj rows, stride 34
    __shared__ __align__(16) float xpw[48*68];    // x_proj rows 0..33 (+zeros), stride 68
    __shared__ __align__(16) float opw[32*68];    // out_proj rows, stride 68
    __shared__ __align__(16) float rowbuf[WPB][128];
    __shared__ __align__(16) float xcbuf[WPB][4*68];   // [t][d], reused as y-buf
    __shared__ __align__(16) float dblbuf[WPB][4*48];  // [t][r] r: 0-1 dt, 2-17 B, 18-33 C

    const int tid = threadIdx.x;
    for (int i = tid; i < 128*32; i += THREADS)
        ipw[(i>>5)*34 + (i&31)] = in_proj_w[i];
    for (int i = tid; i < 48*64; i += THREADS) {
        int r = i >> 6, d = i & 63;
        xpw[r*68 + d] = (r < 34) ? x_proj_w[r*64 + d] : 0.f;
    }
    for (int i = tid; i < 32*64; i += THREADS)
        opw[(i>>6)*68 + (i&63)] = out_proj_w[i];
    __syncthreads();

    const int wid  = tid >> 6;
    const int lane = tid & 63;
    const int tt = lane >> 4;     // t-group for the transposed dots
    const int rr = lane & 15;

    // per-lane persistent params (lane = channel d); loaded once
    const float cw0 = conv_w[lane*4+0], cw1 = conv_w[lane*4+1];
    const float cw2 = conv_w[lane*4+2], cw3 = conv_w[lane*4+3];
    const float cb  = conv_b[lane];
    const float dtw0 = dt_proj_w[lane*2+0], dtw1 = dt_proj_w[lane*2+1];
    const float dtb  = dt_proj_b[lane];
    const float Dd   = Dvec[lane];
    float a_s[16];
    #pragma unroll
    for (int s = 0; s < 16; ++s) a_s[s] = -__expf(A_log[lane*16 + s]);

    for (int n = blockIdx.x*WPB + wid; n < NROWS; n += gridDim.x*WPB) {
        // ---- load row (one sequence: 4 tokens x 32) ----
        rowbuf[wid][lane]      = x[n*128 + lane];
        rowbuf[wid][lane + 64] = x[n*128 + 64 + lane];

        // ---- in_proj: xz[t,j] = sum_g row[t*32+g] * W[j,g]; lane j = lane ----
        float xi0=0.f, xi1=0.f, xi2=0.f, xi3=0.f;
        float z0=0.f, z1=0.f, z2=0.f, z3=0.f;
        {
            const float2* wr1 = (const float2*)&ipw[lane*34];
            const float2* wr2 = (const float2*)&ipw[(lane+64)*34];
            const float2* rb0 = (const float2*)&rowbuf[wid][0];
            const float2* rb1 = (const float2*)&rowbuf[wid][32];
            const float2* rb2 = (const float2*)&rowbuf[wid][64];
            const float2* rb3 = (const float2*)&rowbuf[wid][96];
            #pragma unroll
            for (int g2 = 0; g2 < 16; ++g2) {
                float2 w1 = wr1[g2], w2 = wr2[g2];
                float2 v0 = rb0[g2], v1 = rb1[g2], v2 = rb2[g2], v3 = rb3[g2];
                xi0 += w1.x*v0.x + w1.y*v0.y;  z0 += w2.x*v0.x + w2.y*v0.y;
                xi1 += w1.x*v1.x + w1.y*v1.y;  z1 += w2.x*v1.x + w2.y*v1.y;
                xi2 += w1.x*v2.x + w1.y*v2.y;  z2 += w2.x*v2.x + w2.y*v2.y;
                xi3 += w1.x*v3.x + w1.y*v3.y;  z3 += w2.x*v3.x + w2.y*v3.y;
            }
        }

        // ---- causal depthwise conv (k=4, left pad 3) + SiLU ----
        float xc0 = cb + cw3*xi0;
        float xc1 = cb + cw2*xi0 + cw3*xi1;
        float xc2 = cb + cw1*xi0 + cw2*xi1 + cw3*xi2;
        float xc3 = cb + cw0*xi0 + cw1*xi1 + cw2*xi2 + cw3*xi3;
        xc0 = silu_f(xc0); xc1 = silu_f(xc1); xc2 = silu_f(xc2); xc3 = silu_f(xc3);

        xcbuf[wid][0*68 + lane] = xc0;
        xcbuf[wid][1*68 + lane] = xc1;
        xcbuf[wid][2*68 + lane] = xc2;
        xcbuf[wid][3*68 + lane] = xc3;

        // ---- x_proj: dbl[t,r] = sum_d xc[t,d]*xpw[r,d]; lane=(tt,rr), 3 r's ----
        {
            float acc0=0.f, acc1=0.f, acc2=0.f;
            const float4* xcrow = (const float4*)&xcbuf[wid][tt*68];
            const float4* wA = (const float4*)&xpw[rr*68];
            const float4* wB = (const float4*)&xpw[(rr+16)*68];
            const float4* wC = (const float4*)&xpw[(rr+32)*68];
            #pragma unroll
            for (int k = 0; k < 16; ++k) {
                float4 xv = xcrow[k];
                acc0 += dot4(xv, wA[k]);
                acc1 += dot4(xv, wB[k]);
                acc2 += dot4(xv, wC[k]);
            }
            dblbuf[wid][tt*48 + rr]      = acc0;
            dblbuf[wid][tt*48 + rr + 16] = acc1;
            dblbuf[wid][tt*48 + rr + 32] = acc2;  // rows >=34 are zero-weight garbage, unread
        }

        // ---- delta = softplus(dt @ dt_proj_w.T + b) ----
        float delta[4];
        #pragma unroll
        for (int t = 0; t < 4; ++t) {
            float d0 = dblbuf[wid][t*48 + 0];
            float d1 = dblbuf[wid][t*48 + 1];
            float p = d0*dtw0 + d1*dtw1 + dtb;
            delta[t] = (p > 15.f) ? p : log1pf(__expf(p));
        }

        // ---- selective scan over t=0..3, state h[16] per (row, d=lane) ----
        float h[16];
        #pragma unroll
        for (int s = 0; s < 16; ++s) h[s] = 0.f;
        const float xcv[4] = {xc0, xc1, xc2, xc3};
        float yv[4];
        #pragma unroll
        for (int t = 0; t < 4; ++t) {
            const float2* Bp = (const float2*)&dblbuf[wid][t*48 + 2];
            const float2* Cp = (const float2*)&dblbuf[wid][t*48 + 18];
            const float dt_ = delta[t];
            const float bu  = dt_ * xcv[t];
            float acc = 0.f;
            #pragma unroll
            for (int s2 = 0; s2 < 8; ++s2) {
                float2 Bv = Bp[s2], Cv = Cp[s2];
                int s = s2*2;
                float dA0 = __expf(dt_ * a_s[s]);
                h[s] = dA0*h[s] + bu*Bv.x;  acc += h[s]*Cv.x;
                float dA1 = __expf(dt_ * a_s[s+1]);
                h[s+1] = dA1*h[s+1] + bu*Bv.y;  acc += h[s+1]*Cv.y;
            }
            yv[t] = acc;
        }

        // ---- y = (scan + xc*D) * silu(z); stash into xcbuf (xc regs retained) ----
        {
            const float zz[4] = {z0, z1, z2, z3};
            #pragma unroll
            for (int t = 0; t < 4; ++t) {
                float g = (yv[t] + xcv[t]*Dd) * silu_f(zz[t]);
                xcbuf[wid][t*68 + lane] = g;
            }
        }

        // ---- out_proj: out[t,m] = sum_d y[t,d]*opw[m,d]; lane=(tt,mm), 2 m's ----
        float o0 = 0.f, o1 = 0.f;
        {
            const float4* yrow = (const float4*)&xcbuf[wid][tt*68];
            const float4* u0 = (const float4*)&opw[rr*68];
            const float4* u1 = (const float4*)&opw[(rr+16)*68];
            #pragma unroll
            for (int k = 0; k < 16; ++k) {
                float4 yv4 = yrow[k];
                o0 += dot4(yv4, u0[k]);
                o1 += dot4(yv4, u1[k]);
            }
        }
        float* orow = &xr[n*128];
        orow[tt*32 + rr]      = o0;
        orow[tt*32 + rr + 16] = o1;

        // ---- per-(b,c) stats: row sum / sumsq -> atomics (bc = n>>7) ----
        float s1 = o0 + o1;
        float s2 = o0*o0 + o1*o1;
        #pragma unroll
        for (int off = 32; off > 0; off >>= 1) {
            s1 += __shfl_xor(s1, off, 64);
            s2 += __shfl_xor(s2, off, 64);
        }
        if (lane == 0) {
            atomicAdd(&S1[n >> 7], s1);
            atomicAdd(&S2[n >> 7], s2);
        }
    }
}

// ---------------------------------------------------------------------------
// K2: SE MLP gate + analytic GroupNorm stats -> per-(b,c) alpha/beta
// final = silu(alpha*xr + beta) + x
// ---------------------------------------------------------------------------
__global__ __launch_bounds__(256) void k_se(
    const float* __restrict__ S1, const float* __restrict__ S2,
    const float* __restrict__ se1_w,  // (32,128)
    const float* __restrict__ se2_w,  // (128,32)
    const float* __restrict__ gn_w, const float* __restrict__ gn_b,
    float* __restrict__ alpha, float* __restrict__ beta)
{
    __shared__ float sp[256];   // pooled
    __shared__ float sh[64];    // hidden
    __shared__ float sg[256], st1[256], st2[256];
    __shared__ float smu[8], sinv[8];
    const int tid = threadIdx.x;

    sp[tid] = S1[tid] * (1.f/16384.f);
    __syncthreads();

    if (tid < 64) {
        int b = tid >> 5, j = tid & 31;
        float acc = 0.f;
        for (int c = 0; c < 128; ++c) acc += sp[b*128 + c] * se1_w[j*128 + c];
        sh[tid] = silu_f(acc);
    }
    __syncthreads();

    {
        int b = tid >> 7, c = tid & 127;
        float acc = 0.f;
        #pragma unroll
        for (int j = 0; j < 32; ++j) acc += sh[b*32 + j] * se2_w[c*32 + j];
        float g = 1.f / (1.f + __expf(-acc));
        sg[tid]  = g;
        st1[tid] = g * S1[tid];
        st2[tid] = g * g * S2[tid];
    }
    __syncthreads();

    if (tid < 8) {
        int b = tid >> 2, gr = tid & 3;
        float m = 0.f, q = 0.f;
        for (int c = 0; c < 32; ++c) {
            m += st1[b*128 + gr*32 + c];
            q += st2[b*128 + gr*32 + c];
        }
        const float inv_cnt = 1.f / (32.f * 16384.f);
        m *= inv_cnt; q *= inv_cnt;
        smu[tid]  = m;
        sinv[tid] = rsqrtf(q - m*m + 1e-5f);
    }
    __syncthreads();

    {
        int b = tid >> 7, c = tid & 127;
        int gi = b*4 + (c >> 5);
        float iv = sinv[gi], mu = smu[gi], g = sg[tid], w = gn_w[c];
        alpha[tid] = g * iv * w;
        beta[tid]  = gn_b[c] - mu * iv * w;
    }
}

// ---------------------------------------------------------------------------
// K3: elementwise finish: out = silu(alpha*xr + beta) + x   (in-place on d_out)
// ---------------------------------------------------------------------------
__global__ __launch_bounds__(256) void k_final(
    const float* __restrict__ x, float* __restrict__ o,
    const float* __restrict__ alpha, const float* __restrict__ beta)
{
    const int total4 = (2*128*128*128) / 4;
    const float4* x4 = (const float4*)x;
    float4* o4 = (float4*)o;
    for (int i = blockIdx.x*blockDim.x + threadIdx.x; i < total4;
         i += gridDim.x*blockDim.x) {
        int bc = i >> 12;                 // (i*4) >> 14
        float al = alpha[bc], be = beta[bc];
        float4 v = o4[i], xv = x4[i];
        float u;
        u = al*v.x + be;  v.x = silu_f(u) + xv.x;
        u = al*v.y + be;  v.y = silu_f(u) + xv.y;
        u = al*v.z + be;  v.z = silu_f(u) + xv.z;
        u = al*v.w + be;  v.w = silu_f(u) + xv.w;
        o4[i] = v;
    }
}

extern "C" void kernel_launch(void* const* d_in, const int* in_sizes, int n_in,
                              void* d_out, int out_size, void* d_ws, size_t ws_size,
                              hipStream_t stream) {
    const float* x          = (const float*)d_in[0];
    const float* in_proj_w  = (const float*)d_in[1];
    const float* conv_w     = (const float*)d_in[2];
    const float* conv_b     = (const float*)d_in[3];
    const float* x_proj_w   = (const float*)d_in[4];
    const float* dt_proj_w  = (const float*)d_in[5];
    const float* dt_proj_b  = (const float*)d_in[6];
    const float* A_log      = (const float*)d_in[7];
    const float* Dvec       = (const float*)d_in[8];
    const float* out_proj_w = (const float*)d_in[9];
    const float* se1_w      = (const float*)d_in[10];
    const float* se2_w      = (const float*)d_in[11];
    const float* gn_w       = (const float*)d_in[12];
    const float* gn_b       = (const float*)d_in[13];

    float* out = (float*)d_out;
    float* ws  = (float*)d_ws;
    float* S1 = ws;           // 256
    float* S2 = ws + 256;     // 256
    float* alpha = ws + 512;  // 256
    float* beta  = ws + 768;  // 256

    hipMemsetAsync(ws, 0, 512*sizeof(float), stream);
    k_mamba<<<2048, THREADS, 0, stream>>>(x, in_proj_w, conv_w, conv_b, x_proj_w,
                                          dt_proj_w, dt_proj_b, A_log, Dvec,
                                          out_proj_w, out, S1, S2);
    k_se<<<1, THREADS, 0, stream>>>(S1, S2, se1_w, se2_w, gn_w, gn_b,
                                    ws + 512, ws + 768);
    k_final<<<2048, THREADS, 0, stream>>>(x, out, ws + 512, ws + 768);
}

// Round 2
// 77.356 us; speedup vs baseline: 3.5698x; 3.5698x over previous
//
#include <hip/hip_runtime.h>
#include <math.h>

// ImprovedSpeMamba: b*c*h = 32768 rows; each row = W=128 floats = 4 tokens x 32
#define NROWS 32768
#define NTILES 8192        // 4 rows per wave-tile
#define THREADS 256
#define WPB 4

typedef __attribute__((ext_vector_type(8))) __bf16 bf16x8;
typedef __attribute__((ext_vector_type(4))) float f32x4;

__device__ __forceinline__ float silu_f(float v) {
    return v * __builtin_amdgcn_rcpf(1.f + __expf(-v));
}
__device__ __forceinline__ float softplus_f(float p) {
    return (p > 15.f) ? p : __logf(1.f + __expf(p));
}
__device__ __forceinline__ bf16x8 cvt8v(float4 a, float4 b) {
    bf16x8 r;
    r[0]=(__bf16)a.x; r[1]=(__bf16)a.y; r[2]=(__bf16)a.z; r[3]=(__bf16)a.w;
    r[4]=(__bf16)b.x; r[5]=(__bf16)b.y; r[6]=(__bf16)b.z; r[7]=(__bf16)b.w;
    return r;
}

// ---------------------------------------------------------------------------
// K1: fused mamba. Wave handles 4 rows (M=16 tokens) per tile iteration.
// GEMMs via mfma_f32_16x16x32_bf16; conv+silu in MFMA D-layout (reg = token);
// scan in lane=d layout via LDS staging. Writes xr into d_out.
// ---------------------------------------------------------------------------
__global__ __launch_bounds__(256) void k_mamba(
    const float* __restrict__ x,
    const float* __restrict__ in_proj_w,   // (128,32)
    const float* __restrict__ conv_w,      // (64,4)
    const float* __restrict__ conv_b,      // (64)
    const float* __restrict__ x_proj_w,    // (34,64)
    const float* __restrict__ dt_proj_w,   // (64,2)
    const float* __restrict__ dt_proj_b,   // (64)
    const float* __restrict__ A_log,       // (64,16)
    const float* __restrict__ Dvec,        // (64)
    const float* __restrict__ out_proj_w,  // (32,64)
    float* __restrict__ xr)                // d_out as xr scratch
{
    // B1 (in_proj) fragments, preconverted bf16, frag-layout: [jt][lane] 16B each
    __shared__ __align__(16) __bf16 b1f[8*64*8];              // 8 KiB
    __shared__ __align__(16) float xcb[WPB][16*68];           // xc, later y   (17408 B)
    __shared__ __align__(16) float szb[WPB][16*65];           // silu(z)       (16640 B)
    __shared__ __align__(16) float dbb[WPB][16*40];           // dbl: [m][2+r] (10240 B)

    const int tid  = threadIdx.x;
    const int wid  = tid >> 6;
    const int lane = tid & 63;
    const int c = lane & 15;      // A-row / B-col / D-col within 16-tile
    const int q = lane >> 4;      // K-octet selector / D-row group

    // ---- stage B1 frags (bf16): B[g][j] = in_proj_w[j][g]; lane: col j=c, k=8q+i
    for (int idx = tid; idx < 512; idx += THREADS) {
        int jt = idx >> 6, l = idx & 63, cc = l & 15, qq = l >> 4;
        const float* src = in_proj_w + (jt*16 + cc)*32 + qq*8;
        bf16x8 v;
        #pragma unroll
        for (int i = 0; i < 8; ++i) v[i] = (__bf16)src[i];
        *((bf16x8*)(b1f) + idx) = v;
    }

    // ---- B2 (x_proj) frags in registers: col r = rt*16+c, k = ks*32+8q+i; rows>=34 -> 0
    bf16x8 B2f[2][3];
    #pragma unroll
    for (int ks = 0; ks < 2; ++ks)
        #pragma unroll
        for (int rt = 0; rt < 3; ++rt) {
            int row = rt*16 + c;
            #pragma unroll
            for (int i = 0; i < 8; ++i)
                B2f[ks][rt][i] = (row < 34) ? (__bf16)x_proj_w[row*64 + ks*32 + q*8 + i]
                                            : (__bf16)0.f;
        }
    // ---- B3 (out_proj) frags: col j = jt*16+c
    bf16x8 B3f[2][2];   // [jt][ks]
    #pragma unroll
    for (int jt = 0; jt < 2; ++jt)
        #pragma unroll
        for (int ks = 0; ks < 2; ++ks) {
            int row = jt*16 + c;
            #pragma unroll
            for (int i = 0; i < 8; ++i)
                B3f[jt][ks][i] = (__bf16)out_proj_w[row*64 + ks*32 + q*8 + i];
        }

    // ---- per-lane params: conv per jt (d = jt*16+c); scan params for d = lane
    float cwj[4][4], cbj[4];
    #pragma unroll
    for (int jt = 0; jt < 4; ++jt) {
        int d = jt*16 + c;
        #pragma unroll
        for (int k = 0; k < 4; ++k) cwj[jt][k] = conv_w[d*4 + k];
        cbj[jt] = conv_b[d];
    }
    const float dtw0 = dt_proj_w[lane*2+0], dtw1 = dt_proj_w[lane*2+1];
    const float dtb  = dt_proj_b[lane];
    const float Dd   = Dvec[lane];
    float a_s[16];
    #pragma unroll
    for (int s = 0; s < 16; ++s) a_s[s] = -__expf(A_log[lane*16 + s]);

    __syncthreads();

    float* xc_ = xcb[wid];
    float* sz_ = szb[wid];
    float* db_ = dbb[wid];
    const bf16x8* B1p = (const bf16x8*)b1f;
    const int nwaves = gridDim.x * WPB;

    for (int tile = blockIdx.x*WPB + wid; tile < NTILES; tile += nwaves) {
        const int n0 = tile * 4;                 // 4 rows
        const float* xrow = x + n0*128;

        // ---- A1 frag from global: A[m][g], m=c, g=8q+i (x row-contiguous)
        const float4* xp4 = (const float4*)(xrow + c*32 + q*8);
        bf16x8 A1 = cvt8v(xp4[0], xp4[1]);

        // ---- GEMM1 (8 jt) + conv/silu in D-layout (reg = t), stage xc / silu(z)
        #pragma unroll
        for (int jt = 0; jt < 8; ++jt) {
            f32x4 acc = {0.f, 0.f, 0.f, 0.f};
            acc = __builtin_amdgcn_mfma_f32_16x16x32_bf16(A1, B1p[jt*64 + lane], acc, 0, 0, 0);
            if (jt < 4) {
                const float* cw = cwj[jt];
                float cb = cbj[jt];
                float xc0 = cb + cw[3]*acc[0];
                float xc1 = cb + cw[2]*acc[0] + cw[3]*acc[1];
                float xc2 = cb + cw[1]*acc[0] + cw[2]*acc[1] + cw[3]*acc[2];
                float xc3 = cb + cw[0]*acc[0] + cw[1]*acc[1] + cw[2]*acc[2] + cw[3]*acc[3];
                int dcol = jt*16 + c;
                xc_[(4*q+0)*68 + dcol] = silu_f(xc0);
                xc_[(4*q+1)*68 + dcol] = silu_f(xc1);
                xc_[(4*q+2)*68 + dcol] = silu_f(xc2);
                xc_[(4*q+3)*68 + dcol] = silu_f(xc3);
            } else {
                int dcol = (jt-4)*16 + c;
                #pragma unroll
                for (int t = 0; t < 4; ++t)
                    sz_[(4*q+t)*65 + dcol] = silu_f(acc[t]);
            }
        }

        // ---- A2 frags: read xc[m=c][d = ks*32+8q+i] back (f32 -> bf16)
        bf16x8 A2[2];
        #pragma unroll
        for (int ks = 0; ks < 2; ++ks) {
            const float4* p = (const float4*)&xc_[c*68 + ks*32 + q*8];
            A2[ks] = cvt8v(p[0], p[1]);
        }
        // ---- GEMM2: dbl[m][r]
        f32x4 dacc[3] = {{0,0,0,0},{0,0,0,0},{0,0,0,0}};
        #pragma unroll
        for (int ks = 0; ks < 2; ++ks) {
            dacc[0] = __builtin_amdgcn_mfma_f32_16x16x32_bf16(A2[ks], B2f[ks][0], dacc[0], 0,0,0);
            dacc[1] = __builtin_amdgcn_mfma_f32_16x16x32_bf16(A2[ks], B2f[ks][1], dacc[1], 0,0,0);
            dacc[2] = __builtin_amdgcn_mfma_f32_16x16x32_bf16(A2[ks], B2f[ks][2], dacc[2], 0,0,0);
        }
        // stage dbl: idx = m*40 + 2 + r  (r = rt*16+c; rt==2 only c<4 useful)
        #pragma unroll
        for (int rt = 0; rt < 3; ++rt) {
            if (rt < 2 || c < 4) {
                #pragma unroll
                for (int t = 0; t < 4; ++t)
                    db_[(4*q+t)*40 + 2 + rt*16 + c] = dacc[rt][t];
            }
        }

        // ---- selective scan, lane = d, rows sequential
        #pragma unroll
        for (int r = 0; r < 4; ++r) {
            float h[16];
            #pragma unroll
            for (int s = 0; s < 16; ++s) h[s] = 0.f;
            #pragma unroll
            for (int t = 0; t < 4; ++t) {
                const int m = 4*r + t;
                float2 dtv = *(const float2*)&db_[m*40 + 2];
                float delta = softplus_f(dtv.x*dtw0 + dtv.y*dtw1 + dtb);
                float u  = xc_[m*68 + lane];
                float sz = sz_[m*65 + lane];
                const float4* B4 = (const float4*)&db_[m*40 + 4];
                const float4* C4 = (const float4*)&db_[m*40 + 20];
                const float bu = delta * u;
                float acc = 0.f;
                #pragma unroll
                for (int s2 = 0; s2 < 4; ++s2) {
                    float4 Bv = B4[s2], Cv = C4[s2];
                    int s = s2*4;
                    h[s+0] = __expf(delta*a_s[s+0])*h[s+0] + bu*Bv.x;  acc += h[s+0]*Cv.x;
                    h[s+1] = __expf(delta*a_s[s+1])*h[s+1] + bu*Bv.y;  acc += h[s+1]*Cv.y;
                    h[s+2] = __expf(delta*a_s[s+2])*h[s+2] + bu*Bv.z;  acc += h[s+2]*Cv.z;
                    h[s+3] = __expf(delta*a_s[s+3])*h[s+3] + bu*Bv.w;  acc += h[s+3]*Cv.w;
                }
                float y = (acc + u*Dd) * sz;
                xc_[m*68 + lane] = y;    // overlay xc with gated y
            }
        }

        // ---- A3 frags from y (overlaid) + GEMM3 + store
        bf16x8 A3[2];
        #pragma unroll
        for (int ks = 0; ks < 2; ++ks) {
            const float4* p = (const float4*)&xc_[c*68 + ks*32 + q*8];
            A3[ks] = cvt8v(p[0], p[1]);
        }
        #pragma unroll
        for (int jt = 0; jt < 2; ++jt) {
            f32x4 oacc = {0.f, 0.f, 0.f, 0.f};
            oacc = __builtin_amdgcn_mfma_f32_16x16x32_bf16(A3[0], B3f[jt][0], oacc, 0,0,0);
            oacc = __builtin_amdgcn_mfma_f32_16x16x32_bf16(A3[1], B3f[jt][1], oacc, 0,0,0);
            float* orow = xr + n0*128;
            #pragma unroll
            for (int t = 0; t < 4; ++t)
                orow[(4*q+t)*32 + jt*16 + c] = oacc[t];
        }
    }
}

// ---------------------------------------------------------------------------
// K1b: per-(b,c) plane sum / sumsq (one block per plane, no atomics)
// ---------------------------------------------------------------------------
__global__ __launch_bounds__(256) void k_stats(
    const float* __restrict__ xr, float* __restrict__ S1, float* __restrict__ S2)
{
    const int bc = blockIdx.x;
    const float4* p = (const float4*)(xr + (size_t)bc*16384);
    float s1 = 0.f, s2 = 0.f;
    for (int i = threadIdx.x; i < 4096; i += 256) {
        float4 v = p[i];
        s1 += v.x + v.y + v.z + v.w;
        s2 += v.x*v.x + v.y*v.y + v.z*v.z + v.w*v.w;
    }
    #pragma unroll
    for (int off = 32; off > 0; off >>= 1) {
        s1 += __shfl_xor(s1, off, 64);
        s2 += __shfl_xor(s2, off, 64);
    }
    __shared__ float a1[4], a2[4];
    const int wid = threadIdx.x >> 6;
    if ((threadIdx.x & 63) == 0) { a1[wid] = s1; a2[wid] = s2; }
    __syncthreads();
    if (threadIdx.x == 0) {
        S1[bc] = a1[0]+a1[1]+a1[2]+a1[3];
        S2[bc] = a2[0]+a2[1]+a2[2]+a2[3];
    }
}

// ---------------------------------------------------------------------------
// K2: SE MLP gate + analytic GroupNorm stats -> per-(b,c) alpha/beta
// ---------------------------------------------------------------------------
__global__ __launch_bounds__(256) void k_se(
    const float* __restrict__ S1, const float* __restrict__ S2,
    const float* __restrict__ se1_w,  // (32,128)
    const float* __restrict__ se2_w,  // (128,32)
    const float* __restrict__ gn_w, const float* __restrict__ gn_b,
    float* __restrict__ alpha, float* __restrict__ beta)
{
    __shared__ float sp[256];
    __shared__ float sh[64];
    __shared__ float sg[256], st1[256], st2[256];
    __shared__ float smu[8], sinv[8];
    const int tid = threadIdx.x;

    sp[tid] = S1[tid] * (1.f/16384.f);
    __syncthreads();

    if (tid < 64) {
        int b = tid >> 5, j = tid & 31;
        float acc = 0.f;
        for (int c = 0; c < 128; ++c) acc += sp[b*128 + c] * se1_w[j*128 + c];
        sh[tid] = silu_f(acc);
    }
    __syncthreads();

    {
        int b = tid >> 7, c = tid & 127;
        float acc = 0.f;
        #pragma unroll
        for (int j = 0; j < 32; ++j) acc += sh[b*32 + j] * se2_w[c*32 + j];
        float g = __builtin_amdgcn_rcpf(1.f + __expf(-acc));
        sg[tid]  = g;
        st1[tid] = g * S1[tid];
        st2[tid] = g * g * S2[tid];
    }
    __syncthreads();

    if (tid < 8) {
        int b = tid >> 2, gr = tid & 3;
        float m = 0.f, qq = 0.f;
        for (int c = 0; c < 32; ++c) {
            m  += st1[b*128 + gr*32 + c];
            qq += st2[b*128 + gr*32 + c];
        }
        const float inv_cnt = 1.f / (32.f * 16384.f);
        m *= inv_cnt; qq *= inv_cnt;
        smu[tid]  = m;
        sinv[tid] = rsqrtf(qq - m*m + 1e-5f);
    }
    __syncthreads();

    {
        int b = tid >> 7, c = tid & 127;
        int gi = b*4 + (c >> 5);
        float iv = sinv[gi], mu = smu[gi], g = sg[tid], w = gn_w[c];
        alpha[tid] = g * iv * w;
        beta[tid]  = gn_b[c] - mu * iv * w;
    }
}

// ---------------------------------------------------------------------------
// K3: out = silu(alpha*xr + beta) + x   (in-place on d_out)
// ---------------------------------------------------------------------------
__global__ __launch_bounds__(256) void k_final(
    const float* __restrict__ x, float* __restrict__ o,
    const float* __restrict__ alpha, const float* __restrict__ beta)
{
    const int total4 = (2*128*128*128) / 4;
    const float4* x4 = (const float4*)x;
    float4* o4 = (float4*)o;
    for (int i = blockIdx.x*blockDim.x + threadIdx.x; i < total4;
         i += gridDim.x*blockDim.x) {
        int bc = i >> 12;
        float al = alpha[bc], be = beta[bc];
        float4 v = o4[i], xv = x4[i];
        float u;
        u = al*v.x + be;  v.x = silu_f(u) + xv.x;
        u = al*v.y + be;  v.y = silu_f(u) + xv.y;
        u = al*v.z + be;  v.z = silu_f(u) + xv.z;
        u = al*v.w + be;  v.w = silu_f(u) + xv.w;
        o4[i] = v;
    }
}

extern "C" void kernel_launch(void* const* d_in, const int* in_sizes, int n_in,
                              void* d_out, int out_size, void* d_ws, size_t ws_size,
                              hipStream_t stream) {
    const float* x          = (const float*)d_in[0];
    const float* in_proj_w  = (const float*)d_in[1];
    const float* conv_w     = (const float*)d_in[2];
    const float* conv_b     = (const float*)d_in[3];
    const float* x_proj_w   = (const float*)d_in[4];
    const float* dt_proj_w  = (const float*)d_in[5];
    const float* dt_proj_b  = (const float*)d_in[6];
    const float* A_log      = (const float*)d_in[7];
    const float* Dvec       = (const float*)d_in[8];
    const float* out_proj_w = (const float*)d_in[9];
    const float* se1_w      = (const float*)d_in[10];
    const float* se2_w      = (const float*)d_in[11];
    const float* gn_w       = (const float*)d_in[12];
    const float* gn_b       = (const float*)d_in[13];

    float* out = (float*)d_out;
    float* ws  = (float*)d_ws;
    float* S1 = ws;           // 256
    float* S2 = ws + 256;     // 256
    float* alpha = ws + 512;  // 256
    float* beta  = ws + 768;  // 256

    k_mamba<<<1024, THREADS, 0, stream>>>(x, in_proj_w, conv_w, conv_b, x_proj_w,
                                          dt_proj_w, dt_proj_b, A_log, Dvec,
                                          out_proj_w, out);
    k_stats<<<256, THREADS, 0, stream>>>(out, S1, S2);
    k_se<<<1, THREADS, 0, stream>>>(S1, S2, se1_w, se2_w, gn_w, gn_b, alpha, beta);
    k_final<<<2048, THREADS, 0, stream>>>(x, out, alpha, beta);
}

// Round 3
// 76.053 us; speedup vs baseline: 3.6309x; 1.0171x over previous
//
#include <hip/hip_runtime.h>
#include <math.h>

// ImprovedSpeMamba: b*c*h = 32768 rows; each row = W=128 floats = 4 tokens x 32
#define NROWS 32768
#define NTILES 8192        // 4 rows per wave-tile
#define THREADS 256
#define WPB 4

typedef __attribute__((ext_vector_type(8))) __bf16 bf16x8;
typedef __attribute__((ext_vector_type(4))) float f32x4;

__device__ __forceinline__ float silu_f(float v) {
    return v * __builtin_amdgcn_rcpf(1.f + __expf(-v));
}
__device__ __forceinline__ bf16x8 cvt8v(float4 a, float4 b) {
    bf16x8 r;
    r[0]=(__bf16)a.x; r[1]=(__bf16)a.y; r[2]=(__bf16)a.z; r[3]=(__bf16)a.w;
    r[4]=(__bf16)b.x; r[5]=(__bf16)b.y; r[6]=(__bf16)b.z; r[7]=(__bf16)b.w;
    return r;
}

// ---------------------------------------------------------------------------
// K1: fused mamba. Wave = 4 rows (M=16 tokens). GEMMs via mfma 16x16x32 bf16.
// Scan fast-path: dA_s = e1^(s+1) with e1 = rcp(1+e^p)  (exact when
// A_log = log(1..16); runtime-guarded with generic fallback).
// Also accumulates per-(b,c) sum/sumsq for SE+GN (atomics).
// ---------------------------------------------------------------------------
__global__ __launch_bounds__(256) void k_mamba(
    const float* __restrict__ x,
    const float* __restrict__ in_proj_w,   // (128,32)
    const float* __restrict__ conv_w,      // (64,4)
    const float* __restrict__ conv_b,      // (64)
    const float* __restrict__ x_proj_w,    // (34,64)
    const float* __restrict__ dt_proj_w,   // (64,2)
    const float* __restrict__ dt_proj_b,   // (64)
    const float* __restrict__ A_log,       // (64,16)
    const float* __restrict__ Dvec,        // (64)
    const float* __restrict__ out_proj_w,  // (32,64)
    float* __restrict__ xr,                // d_out as xr scratch
    float* __restrict__ S1, float* __restrict__ S2)
{
    __shared__ __align__(16) __bf16 b1f[8*64*8];          // 8 KiB B1 frags
    __shared__ __align__(16) float xcb[WPB][16*68];       // xc, later y
    __shared__ __align__(16) float szb[WPB][16*66];       // silu(z) (2-way banks)
    __shared__ __align__(16) float dbb[WPB][16*44];       // dbl rows (2-way banks)

    const int tid  = threadIdx.x;
    const int wid  = tid >> 6;
    const int lane = tid & 63;
    const int c = lane & 15;      // A-row / B-col / D-col within 16-tile
    const int q = lane >> 4;      // K-octet selector / D-row group

    // ---- stage B1 frags (bf16): lane: col j=c, k=8q+i
    for (int idx = tid; idx < 512; idx += THREADS) {
        int jt = idx >> 6, l = idx & 63, cc = l & 15, qq = l >> 4;
        const float* src = in_proj_w + (jt*16 + cc)*32 + qq*8;
        bf16x8 v;
        #pragma unroll
        for (int i = 0; i < 8; ++i) v[i] = (__bf16)src[i];
        *((bf16x8*)(b1f) + idx) = v;
    }

    // ---- B2 (x_proj) frags in regs: col r = rt*16+c, k = ks*32+8q+i
    bf16x8 B2f[2][3];
    #pragma unroll
    for (int ks = 0; ks < 2; ++ks)
        #pragma unroll
        for (int rt = 0; rt < 3; ++rt) {
            int row = rt*16 + c;
            #pragma unroll
            for (int i = 0; i < 8; ++i)
                B2f[ks][rt][i] = (row < 34) ? (__bf16)x_proj_w[row*64 + ks*32 + q*8 + i]
                                            : (__bf16)0.f;
        }
    // ---- B3 (out_proj) frags
    bf16x8 B3f[2][2];   // [jt][ks]
    #pragma unroll
    for (int jt = 0; jt < 2; ++jt)
        #pragma unroll
        for (int ks = 0; ks < 2; ++ks) {
            int row = jt*16 + c;
            #pragma unroll
            for (int i = 0; i < 8; ++i)
                B3f[jt][ks][i] = (__bf16)out_proj_w[row*64 + ks*32 + q*8 + i];
        }

    // ---- per-lane params
    float cwj[4][4], cbj[4];
    #pragma unroll
    for (int jt = 0; jt < 4; ++jt) {
        int d = jt*16 + c;
        #pragma unroll
        for (int k = 0; k < 4; ++k) cwj[jt][k] = conv_w[d*4 + k];
        cbj[jt] = conv_b[d];
    }
    const float dtw0 = dt_proj_w[lane*2+0], dtw1 = dt_proj_w[lane*2+1];
    const float dtb  = dt_proj_b[lane];
    const float Dd   = Dvec[lane];

    // ---- fast-A check: A_log == log(1..16) (wave-uniform)
    bool okl = true;
    #pragma unroll
    for (int s = 0; s < 16; ++s) {
        float a = __expf(A_log[lane*16 + s]);
        okl = okl && (fabsf(a - (float)(s+1)) < 1e-3f * (float)(s+1));
    }
    const bool fastA = (__ballot(okl) == ~0ull);

    __syncthreads();

    float* xc_ = xcb[wid];
    float* sz_ = szb[wid];
    float* db_ = dbb[wid];
    const bf16x8* B1p = (const bf16x8*)b1f;
    const int nwaves = gridDim.x * WPB;

    for (int tile = blockIdx.x*WPB + wid; tile < NTILES; tile += nwaves) {
        const int n0 = tile * 4;                 // 4 rows, same (b,c) plane
        const float* xrow = x + n0*128;

        // ---- A1 frag from global (x row-contiguous)
        const float4* xp4 = (const float4*)(xrow + c*32 + q*8);
        bf16x8 A1 = cvt8v(xp4[0], xp4[1]);

        // ---- GEMM1 (8 jt) + conv/silu in D-layout (reg = token)
        #pragma unroll
        for (int jt = 0; jt < 8; ++jt) {
            f32x4 acc = {0.f, 0.f, 0.f, 0.f};
            acc = __builtin_amdgcn_mfma_f32_16x16x32_bf16(A1, B1p[jt*64 + lane], acc, 0, 0, 0);
            if (jt < 4) {
                const float* cw = cwj[jt];
                float cb = cbj[jt];
                float xc0 = cb + cw[3]*acc[0];
                float xc1 = cb + cw[2]*acc[0] + cw[3]*acc[1];
                float xc2 = cb + cw[1]*acc[0] + cw[2]*acc[1] + cw[3]*acc[2];
                float xc3 = cb + cw[0]*acc[0] + cw[1]*acc[1] + cw[2]*acc[2] + cw[3]*acc[3];
                int dcol = jt*16 + c;
                xc_[(4*q+0)*68 + dcol] = silu_f(xc0);
                xc_[(4*q+1)*68 + dcol] = silu_f(xc1);
                xc_[(4*q+2)*68 + dcol] = silu_f(xc2);
                xc_[(4*q+3)*68 + dcol] = silu_f(xc3);
            } else {
                int dcol = (jt-4)*16 + c;
                #pragma unroll
                for (int t = 0; t < 4; ++t)
                    sz_[(4*q+t)*66 + dcol] = silu_f(acc[t]);
            }
        }

        // ---- A2 frags from xc (f32 -> bf16)
        bf16x8 A2[2];
        #pragma unroll
        for (int ks = 0; ks < 2; ++ks) {
            const float4* p = (const float4*)&xc_[c*68 + ks*32 + q*8];
            A2[ks] = cvt8v(p[0], p[1]);
        }
        // ---- GEMM2: dbl[m][r]
        f32x4 dacc[3] = {{0,0,0,0},{0,0,0,0},{0,0,0,0}};
        #pragma unroll
        for (int ks = 0; ks < 2; ++ks) {
            dacc[0] = __builtin_amdgcn_mfma_f32_16x16x32_bf16(A2[ks], B2f[ks][0], dacc[0], 0,0,0);
            dacc[1] = __builtin_amdgcn_mfma_f32_16x16x32_bf16(A2[ks], B2f[ks][1], dacc[1], 0,0,0);
            dacc[2] = __builtin_amdgcn_mfma_f32_16x16x32_bf16(A2[ks], B2f[ks][2], dacc[2], 0,0,0);
        }
        // stage dbl: db_[m*44 + 2 + r], r = rt*16+c
        #pragma unroll
        for (int rt = 0; rt < 3; ++rt) {
            if (rt < 2 || c < 4) {
                #pragma unroll
                for (int t = 0; t < 4; ++t)
                    db_[(4*q+t)*44 + 2 + rt*16 + c] = dacc[rt][t];
            }
        }

        // ---- selective scan, lane = d, rows sequential
        #pragma unroll
        for (int r = 0; r < 4; ++r) {
            float h[16];
            #pragma unroll
            for (int s = 0; s < 16; ++s) h[s] = 0.f;
            #pragma unroll
            for (int t = 0; t < 4; ++t) {
                const int m = 4*r + t;
                float2 dtv = *(const float2*)&db_[m*44 + 2];
                float p  = fmaf(dtv.y, dtw1, fmaf(dtv.x, dtw0, dtb));
                float ex = __expf(p);
                float t1 = 1.f + ex;
                float e1 = __builtin_amdgcn_rcpf(t1);       // exp(-softplus(p)) exactly
                float delta = (p > 15.f) ? p : __logf(t1);  // softplus(p)
                float u  = xc_[m*68 + lane];
                float sz = sz_[m*66 + lane];
                const float bu = delta * u;

                float dA[16];
                if (fastA) {
                    float e2 = e1*e1, e4 = e2*e2, e8 = e4*e4;
                    dA[0]=e1;      dA[1]=e2;      dA[2]=e2*e1;    dA[3]=e4;
                    dA[4]=e4*e1;   dA[5]=e4*e2;   dA[6]=e4*dA[2]; dA[7]=e8;
                    dA[8]=e8*e1;   dA[9]=e8*e2;   dA[10]=e8*dA[2];dA[11]=e8*e4;
                    dA[12]=e8*dA[4];dA[13]=e8*dA[5];dA[14]=e8*dA[6];dA[15]=e8*e8;
                } else {
                    #pragma unroll
                    for (int s = 0; s < 16; ++s)
                        dA[s] = __expf(-delta * __expf(A_log[lane*16 + s]));
                }

                const float4* B4 = (const float4*)&db_[m*44 + 4];
                const float4* C4 = (const float4*)&db_[m*44 + 20];
                float acc = 0.f;
                #pragma unroll
                for (int s2 = 0; s2 < 4; ++s2) {
                    float4 Bv = B4[s2], Cv = C4[s2];
                    int s = s2*4;
                    h[s+0] = dA[s+0]*h[s+0] + bu*Bv.x;  acc += h[s+0]*Cv.x;
                    h[s+1] = dA[s+1]*h[s+1] + bu*Bv.y;  acc += h[s+1]*Cv.y;
                    h[s+2] = dA[s+2]*h[s+2] + bu*Bv.z;  acc += h[s+2]*Cv.z;
                    h[s+3] = dA[s+3]*h[s+3] + bu*Bv.w;  acc += h[s+3]*Cv.w;
                }
                float y = (acc + u*Dd) * sz;
                xc_[m*68 + lane] = y;    // overlay xc with gated y
            }
        }

        // ---- A3 frags from y + GEMM3 + store + stats
        bf16x8 A3[2];
        #pragma unroll
        for (int ks = 0; ks < 2; ++ks) {
            const float4* p = (const float4*)&xc_[c*68 + ks*32 + q*8];
            A3[ks] = cvt8v(p[0], p[1]);
        }
        float s1 = 0.f, s2 = 0.f;
        float* orow = xr + n0*128;
        #pragma unroll
        for (int jt = 0; jt < 2; ++jt) {
            f32x4 oacc = {0.f, 0.f, 0.f, 0.f};
            oacc = __builtin_amdgcn_mfma_f32_16x16x32_bf16(A3[0], B3f[jt][0], oacc, 0,0,0);
            oacc = __builtin_amdgcn_mfma_f32_16x16x32_bf16(A3[1], B3f[jt][1], oacc, 0,0,0);
            #pragma unroll
            for (int t = 0; t < 4; ++t) {
                orow[(4*q+t)*32 + jt*16 + c] = oacc[t];
                s1 += oacc[t];
                s2 += oacc[t]*oacc[t];
            }
        }
        #pragma unroll
        for (int off = 32; off > 0; off >>= 1) {
            s1 += __shfl_xor(s1, off, 64);
            s2 += __shfl_xor(s2, off, 64);
        }
        if (lane == 0) {
            atomicAdd(&S1[tile >> 5], s1);
            atomicAdd(&S2[tile >> 5], s2);
        }
    }
}

// ---------------------------------------------------------------------------
// K2: SE MLP gate + analytic GroupNorm stats -> per-(b,c) alpha/beta
// ---------------------------------------------------------------------------
__global__ __launch_bounds__(256) void k_se(
    const float* __restrict__ S1, const float* __restrict__ S2,
    const float* __restrict__ se1_w,  // (32,128)
    const float* __restrict__ se2_w,  // (128,32)
    const float* __restrict__ gn_w, const float* __restrict__ gn_b,
    float* __restrict__ alpha, float* __restrict__ beta)
{
    __shared__ float sp[256];
    __shared__ float sh[64];
    __shared__ float sg[256], st1[256], st2[256];
    __shared__ float smu[8], sinv[8];
    const int tid = threadIdx.x;

    sp[tid] = S1[tid] * (1.f/16384.f);
    __syncthreads();

    if (tid < 64) {
        int b = tid >> 5, j = tid & 31;
        float acc = 0.f;
        for (int c = 0; c < 128; ++c) acc += sp[b*128 + c] * se1_w[j*128 + c];
        sh[tid] = silu_f(acc);
    }
    __syncthreads();

    {
        int b = tid >> 7, c = tid & 127;
        float acc = 0.f;
        #pragma unroll
        for (int j = 0; j < 32; ++j) acc += sh[b*32 + j] * se2_w[c*32 + j];
        float g = __builtin_amdgcn_rcpf(1.f + __expf(-acc));
        sg[tid]  = g;
        st1[tid] = g * S1[tid];
        st2[tid] = g * g * S2[tid];
    }
    __syncthreads();

    if (tid < 8) {
        int b = tid >> 2, gr = tid & 3;
        float m = 0.f, qq = 0.f;
        for (int c = 0; c < 32; ++c) {
            m  += st1[b*128 + gr*32 + c];
            qq += st2[b*128 + gr*32 + c];
        }
        const float inv_cnt = 1.f / (32.f * 16384.f);
        m *= inv_cnt; qq *= inv_cnt;
        smu[tid]  = m;
        sinv[tid] = rsqrtf(qq - m*m + 1e-5f);
    }
    __syncthreads();

    {
        int b = tid >> 7, c = tid & 127;
        int gi = b*4 + (c >> 5);
        float iv = sinv[gi], mu = smu[gi], g = sg[tid], w = gn_w[c];
        alpha[tid] = g * iv * w;
        beta[tid]  = gn_b[c] - mu * iv * w;
    }
}

// ---------------------------------------------------------------------------
// K3: out = silu(alpha*xr + beta) + x   (in-place on d_out)
// ---------------------------------------------------------------------------
__global__ __launch_bounds__(256) void k_final(
    const float* __restrict__ x, float* __restrict__ o,
    const float* __restrict__ alpha, const float* __restrict__ beta)
{
    const int total4 = (2*128*128*128) / 4;
    const float4* x4 = (const float4*)x;
    float4* o4 = (float4*)o;
    for (int i = blockIdx.x*blockDim.x + threadIdx.x; i < total4;
         i += gridDim.x*blockDim.x) {
        int bc = i >> 12;
        float al = alpha[bc], be = beta[bc];
        float4 v = o4[i], xv = x4[i];
        float u;
        u = al*v.x + be;  v.x = silu_f(u) + xv.x;
        u = al*v.y + be;  v.y = silu_f(u) + xv.y;
        u = al*v.z + be;  v.z = silu_f(u) + xv.z;
        u = al*v.w + be;  v.w = silu_f(u) + xv.w;
        o4[i] = v;
    }
}

extern "C" void kernel_launch(void* const* d_in, const int* in_sizes, int n_in,
                              void* d_out, int out_size, void* d_ws, size_t ws_size,
                              hipStream_t stream) {
    const float* x          = (const float*)d_in[0];
    const float* in_proj_w  = (const float*)d_in[1];
    const float* conv_w     = (const float*)d_in[2];
    const float* conv_b     = (const float*)d_in[3];
    const float* x_proj_w   = (const float*)d_in[4];
    const float* dt_proj_w  = (const float*)d_in[5];
    const float* dt_proj_b  = (const float*)d_in[6];
    const float* A_log      = (const float*)d_in[7];
    const float* Dvec       = (const float*)d_in[8];
    const float* out_proj_w = (const float*)d_in[9];
    const float* se1_w      = (const float*)d_in[10];
    const float* se2_w      = (const float*)d_in[11];
    const float* gn_w       = (const float*)d_in[12];
    const float* gn_b       = (const float*)d_in[13];

    float* out = (float*)d_out;
    float* ws  = (float*)d_ws;
    float* S1 = ws;           // 256
    float* S2 = ws + 256;     // 256
    float* alpha = ws + 512;  // 256
    float* beta  = ws + 768;  // 256

    hipMemsetAsync(ws, 0, 512*sizeof(float), stream);
    k_mamba<<<768, THREADS, 0, stream>>>(x, in_proj_w, conv_w, conv_b, x_proj_w,
                                         dt_proj_w, dt_proj_b, A_log, Dvec,
                                         out_proj_w, out, S1, S2);
    k_se<<<1, THREADS, 0, stream>>>(S1, S2, se1_w, se2_w, gn_w, gn_b, alpha, beta);
    k_final<<<2048, THREADS, 0, stream>>>(x, out, alpha, beta);
}